// Round 1
// baseline (3030.039 us; speedup 1.0000x reference)
//
#include <hip/hip_runtime.h>
#include <hip/hip_bf16.h>

// ---------------------------------------------------------------------------
// Encoder: emb gather -> LSTM0 -> LSTM1 -> BatchNorm(inference)
// B=64, T=128, D=256, H=1024, 4H=4096, BT=8192 rows.
//
// Layout decisions:
//  - Gate columns permuted: pc = j*4 + gate   (gate = col/1024, j = col%1024)
//    so one 16-col MFMA N-tile holds 4 h-columns x 4 gates (epilogue-local).
//  - Weights stored transposed+permuted: UbT[pc][k], WbT[pc][k] (bf16) so
//    MFMA B-fragments are contiguous 16B loads (same pattern as A).
//  - XW[t*64+b][pc] precomputed (bf16) for both layers; layer1's XW GEMM runs
//    after layer0's recurrence using saved H0all[t*64+b][j] (bf16).
//  - h ping-pongs between two bf16 buffers (read-set != write-set per step);
//    c/h f32 state is exclusively owned per (b,j) lane -> no double buffer.
// ---------------------------------------------------------------------------

typedef __attribute__((ext_vector_type(8))) short short8;
typedef __attribute__((ext_vector_type(4))) float f32x4;
typedef unsigned short ushort_t;

__device__ __forceinline__ ushort_t f2b(float f) {
  __hip_bfloat16 h = __float2bfloat16(f);
  return *reinterpret_cast<ushort_t*>(&h);
}
__device__ __forceinline__ float b2f(ushort_t u) {
  unsigned int x = ((unsigned int)u) << 16;
  return __builtin_bit_cast(float, x);
}

// ---- convert W/U [K][4096] f32 -> dst[pc][k] bf16 (transposed + permuted) --
__global__ __launch_bounds__(256) void k_convert_bt(
    const float* __restrict__ src, ushort_t* __restrict__ dst, int kshift) {
  int tid = blockIdx.x * 256 + threadIdx.x;       // tid = pc*K + k
  int K = 1 << kshift;
  int pc = tid >> kshift;
  int k = tid & (K - 1);
  int c = ((pc & 3) << 10) | (pc >> 2);           // original column
  dst[tid] = f2b(src[(size_t)k * 4096 + c]);
}

// ---- permute biases -------------------------------------------------------
__global__ __launch_bounds__(256) void k_bias(
    const float* __restrict__ b0, const float* __restrict__ b1,
    float* __restrict__ bp0, float* __restrict__ bp1) {
  int pc = blockIdx.x * 256 + threadIdx.x;
  int c = ((pc & 3) << 10) | (pc >> 2);
  bp0[pc] = b0[c];
  bp1[pc] = b1[c];
}

// ---- embedding gather: Xemb[(t*64+b)][d] = bf16(emb[tokens[b][t]][d]) -----
__global__ __launch_bounds__(256) void k_gather(
    const int* __restrict__ tokens, const float* __restrict__ emb,
    ushort_t* __restrict__ Xemb) {
  int row = blockIdx.x;            // row = t*64 + b
  int t = row >> 6, b = row & 63;
  int tok = tokens[b * 128 + t];
  int d = threadIdx.x;
  Xemb[(size_t)row * 256 + d] = f2b(emb[(size_t)tok * 256 + d]);
}

// ---- state init -----------------------------------------------------------
__global__ __launch_bounds__(256) void k_init(
    const float* __restrict__ h0, const float* __restrict__ c0,
    ushort_t* __restrict__ hbA, float* __restrict__ h_st,
    float* __restrict__ c_st) {
  int tid = blockIdx.x * 256 + threadIdx.x;
  hbA[tid] = f2b(h0[tid]);
  h_st[tid] = h0[tid];
  c_st[tid] = c0[tid];
}

// ---- bf16 GEMM: C[8192][4096] = A[8192][K] * BT[4096][K]^T ----------------
// 128x128 tile/WG, 4 waves as 2x2, 64x64/wave (4x4 MFMA tiles), direct L2.
__global__ __launch_bounds__(256) void k_gemm_bt(
    const ushort_t* __restrict__ A, const ushort_t* __restrict__ BT,
    ushort_t* __restrict__ C, int K) {
  const int l = threadIdx.x & 63;
  const int wv = threadIdx.x >> 6;
  const int wvM = wv & 1, wvN = wv >> 1;
  const int wgM = blockIdx.x & 63;     // 8192/128
  const int wgN = blockIdx.x >> 6;     // 4096/128
  const int koff = (l >> 4) * 8;

  f32x4 acc[4][4] = {};
  const ushort_t* Ap = A + (size_t)(wgM * 128 + wvM * 64 + (l & 15)) * K + koff;
  const ushort_t* Bp = BT + (size_t)(wgN * 128 + wvN * 64 + (l & 15)) * K + koff;

  for (int k0 = 0; k0 < K; k0 += 32) {
    short8 a[4], b[4];
#pragma unroll
    for (int mt = 0; mt < 4; ++mt)
      a[mt] = *(const short8*)(Ap + (size_t)mt * 16 * K + k0);
#pragma unroll
    for (int nt = 0; nt < 4; ++nt)
      b[nt] = *(const short8*)(Bp + (size_t)nt * 16 * K + k0);
#pragma unroll
    for (int mt = 0; mt < 4; ++mt)
#pragma unroll
      for (int nt = 0; nt < 4; ++nt)
        acc[mt][nt] =
            __builtin_amdgcn_mfma_f32_16x16x32_bf16(a[mt], b[nt], acc[mt][nt], 0, 0, 0);
  }

  const int rr0 = wgM * 128 + wvM * 64 + (l >> 4) * 4;
  const int cc0 = wgN * 128 + wvN * 64 + (l & 15);
#pragma unroll
  for (int mt = 0; mt < 4; ++mt)
#pragma unroll
    for (int nt = 0; nt < 4; ++nt)
#pragma unroll
      for (int r = 0; r < 4; ++r)
        C[(size_t)(rr0 + mt * 16 + r) * 4096 + cc0 + nt * 16] =
            f2b(acc[mt][nt][r]);
}

// ---- one LSTM timestep ----------------------------------------------------
// Grid 256 WGs = 4 M-blocks(16 rows) x 64 N-blocks(64 permuted cols).
// 4 waves/WG, each computes one 16x16 z-tile over K=1024, then gate epilogue.
__global__ __launch_bounds__(256) void k_lstm_step(
    const ushort_t* __restrict__ hb,    // [64][1024] bf16 (step input)
    const ushort_t* __restrict__ UbT,   // [4096][1024] bf16
    const ushort_t* __restrict__ XWt,   // [64][4096] bf16 (this t)
    const float* __restrict__ biasp,    // [4096] permuted
    float* __restrict__ c_st,           // [64][1024] f32 in/out
    float* __restrict__ h_st,           // [64][1024] f32 out
    ushort_t* __restrict__ hb_out,      // [64][1024] bf16 out
    ushort_t* __restrict__ Hsave,       // layer0: H0all + t*65536, else null
    float* __restrict__ norm_out,       // layer1: d_out, else null
    const float* __restrict__ gamma, const float* __restrict__ beta,
    const float* __restrict__ mean, const float* __restrict__ var, int t) {
  const int l = threadIdx.x & 63;
  const int wv = threadIdx.x >> 6;
  const int wgM = blockIdx.x & 3;
  const int wgN = blockIdx.x >> 2;
  const int row = wgM * 16 + (l & 15);
  const int pc = wgN * 64 + wv * 16 + (l & 15);
  const int koff = (l >> 4) * 8;

  f32x4 acc = {0.f, 0.f, 0.f, 0.f};
  const ushort_t* Ap = hb + (size_t)row * 1024 + koff;
  const ushort_t* Bp = UbT + (size_t)pc * 1024 + koff;
#pragma unroll 8
  for (int k0 = 0; k0 < 1024; k0 += 32) {
    short8 a = *(const short8*)(Ap + k0);
    short8 b = *(const short8*)(Bp + k0);
    acc = __builtin_amdgcn_mfma_f32_16x16x32_bf16(a, b, acc, 0, 0, 0);
  }

  __shared__ float zbuf[4][16][16];
  const int drow = (l >> 4) * 4;
#pragma unroll
  for (int r = 0; r < 4; ++r) {
    int rb = wgM * 16 + drow + r;
    float z = acc[r] + b2f(XWt[(size_t)rb * 4096 + pc]) + biasp[pc];
    zbuf[wv][drow + r][l & 15] = z;
  }
  __syncthreads();

  const int b_loc = l & 15, jl = l >> 4;
  float zi = zbuf[wv][b_loc][jl * 4 + 0];
  float zf = zbuf[wv][b_loc][jl * 4 + 1];
  float zg = zbuf[wv][b_loc][jl * 4 + 2];
  float zo = zbuf[wv][b_loc][jl * 4 + 3];
  const int b = wgM * 16 + b_loc;
  const int j = wgN * 16 + wv * 4 + jl;
  const size_t idx = (size_t)b * 1024 + j;

  float co = c_st[idx];
  float ii = 1.f / (1.f + expf(-zi));
  float ff = 1.f / (1.f + expf(-zf));
  float oo = 1.f / (1.f + expf(-zo));
  float gg = tanhf(zg);
  float cn = ff * co + ii * gg;
  float hn = oo * tanhf(cn);

  c_st[idx] = cn;
  h_st[idx] = hn;
  hb_out[idx] = f2b(hn);
  if (Hsave) Hsave[idx] = f2b(hn);
  if (norm_out) {
    float nm = (hn - mean[j]) * rsqrtf(var[j] + 1e-3f) * gamma[j] + beta[j];
    norm_out[((size_t)b * 128 + t) * 1024 + j] = nm;
  }
}

// ---- final h,c copy -------------------------------------------------------
__global__ __launch_bounds__(256) void k_final(
    const float* __restrict__ h_st, const float* __restrict__ c_st,
    float* __restrict__ out) {
  int tid = blockIdx.x * 256 + threadIdx.x;
  out[8388608 + tid] = h_st[tid];
  out[8454144 + tid] = c_st[tid];
}

extern "C" void kernel_launch(void* const* d_in, const int* in_sizes, int n_in,
                              void* d_out, int out_size, void* d_ws,
                              size_t ws_size, hipStream_t stream) {
  const int* tokens = (const int*)d_in[0];
  const float* h0 = (const float*)d_in[1];
  const float* c0 = (const float*)d_in[2];
  const float* emb = (const float*)d_in[3];
  const float* W0 = (const float*)d_in[4];
  const float* U0 = (const float*)d_in[5];
  const float* b0 = (const float*)d_in[6];
  const float* W1 = (const float*)d_in[7];
  const float* U1 = (const float*)d_in[8];
  const float* b1 = (const float*)d_in[9];
  const float* gamma = (const float*)d_in[10];
  const float* beta = (const float*)d_in[11];
  const float* mmean = (const float*)d_in[12];
  const float* mvar = (const float*)d_in[13];

  char* ws = (char*)d_ws;
  ushort_t* UbT0 = (ushort_t*)(ws + 0);            //  8 MB [4096][1024]
  ushort_t* UbT1 = (ushort_t*)(ws + 8388608);      //  8 MB
  ushort_t* WbT0 = (ushort_t*)(ws + 16777216);     //  2 MB [4096][256]
  ushort_t* WbT1 = (ushort_t*)(ws + 18874368);     //  8 MB [4096][1024]
  float* bp0 = (float*)(ws + 27262976);            // 16 KB
  float* bp1 = (float*)(ws + 27279360);            // 16 KB
  ushort_t* Xemb = (ushort_t*)(ws + 27295744);     //  4 MB [8192][256]
  ushort_t* XW = (ushort_t*)(ws + 31490048);       // 64 MB [8192][4096]
  ushort_t* H0all = (ushort_t*)(ws + 98598912);    // 16 MB [8192][1024]
  ushort_t* hbA = (ushort_t*)(ws + 115376128);     // 128 KB
  ushort_t* hbB = (ushort_t*)(ws + 115507200);     // 128 KB
  float* h_st = (float*)(ws + 115638272);          // 256 KB
  float* c_st = (float*)(ws + 115900416);          // 256 KB

  // weight conversion (transpose + gate-permute, f32->bf16)
  k_convert_bt<<<16384, 256, 0, stream>>>(U0, UbT0, 10);
  k_convert_bt<<<16384, 256, 0, stream>>>(U1, UbT1, 10);
  k_convert_bt<<<4096, 256, 0, stream>>>(W0, WbT0, 8);
  k_convert_bt<<<16384, 256, 0, stream>>>(W1, WbT1, 10);
  k_bias<<<16, 256, 0, stream>>>(b0, b1, bp0, bp1);
  k_gather<<<8192, 256, 0, stream>>>(tokens, emb, Xemb);
  k_init<<<256, 256, 0, stream>>>(h0, c0, hbA, h_st, c_st);

  // layer 0: XW = Xemb @ W0 (K=256), then recurrence
  k_gemm_bt<<<2048, 256, 0, stream>>>(Xemb, WbT0, XW, 256);
  for (int t = 0; t < 128; ++t) {
    const ushort_t* hin = (t & 1) ? hbB : hbA;
    ushort_t* hout = (t & 1) ? hbA : hbB;
    k_lstm_step<<<256, 256, 0, stream>>>(
        hin, UbT0, XW + (size_t)t * 64 * 4096, bp0, c_st, h_st, hout,
        H0all + (size_t)t * 64 * 1024, nullptr, nullptr, nullptr, nullptr,
        nullptr, t);
  }

  // layer 1: XW = H0all @ W1 (K=1024), then recurrence (state carries over)
  k_gemm_bt<<<2048, 256, 0, stream>>>(H0all, WbT1, XW, 1024);
  for (int t = 0; t < 128; ++t) {
    const ushort_t* hin = (t & 1) ? hbB : hbA;
    ushort_t* hout = (t & 1) ? hbA : hbB;
    k_lstm_step<<<256, 256, 0, stream>>>(
        hin, UbT1, XW + (size_t)t * 64 * 4096, bp1, c_st, h_st, hout, nullptr,
        (float*)d_out, gamma, beta, mmean, mvar, t);
  }

  k_final<<<256, 256, 0, stream>>>(h_st, c_st, (float*)d_out);
}